// Round 10
// baseline (373.746 us; speedup 1.0000x reference)
//
#include <hip/hip_runtime.h>
#include <math.h>

typedef __attribute__((ext_vector_type(8))) short short8v;   // 8 bf16 = 4 VGPRs
typedef __attribute__((ext_vector_type(4))) float float4v;   // MFMA acc

constexpr int Bsz = 8, Tn = 16, CINc = 6, Fc = 64, NCc = 10;
constexpr int PIX = 8192;                 // 8*32*32 pixels per timestep
constexpr float BN_EPS = 1e-3f;

// weight-fragment region offsets (in ushort elements)
constexpr int FR_L0X = 0;                 // 2 chunks  (K=54 padded to 64)
constexpr int FR_L0H = 16384;             // 18 chunks (K=576)
constexpr int FR_L1X = 163840;            // 18 chunks
constexpr int FR_L1H = 311296;            // 18 chunks
constexpr int FR_TOTAL = 458752;

__device__ __forceinline__ ushort f2bf(float f) {
    union { float f; unsigned u; } v; v.f = f;
    unsigned r = v.u + 0x7FFFu + ((v.u >> 16) & 1u);   // RNE
    return (ushort)(r >> 16);
}
__device__ __forceinline__ float bf2f(ushort u) {
    union { unsigned u; float f; } v; v.u = ((unsigned)u) << 16; return v.f;
}
__device__ __forceinline__ float hsig(float x) {
    return fminf(fmaxf(0.2f * x + 0.5f, 0.0f), 1.0f);
}

#define GLDS(srcp, dstp) \
    __builtin_amdgcn_global_load_lds((const __attribute__((address_space(1))) void*)(srcp), \
                                     (__attribute__((address_space(3))) void*)(dstp), 16, 0, 0)

// ---------------- prep: x -> bf16 [t][pix][6] ----------------
__global__ __launch_bounds__(256) void prep_x(const float* __restrict__ in,
                                              ushort* __restrict__ xb) {
    int o = blockIdx.x * 256 + threadIdx.x;        // 16*8192*6 = 786432
    if (o >= Tn * PIX * CINc) return;
    int t = o / (PIX * CINc);
    int rem = o - t * (PIX * CINc);
    int pix = rem / CINc, c = rem - pix * CINc;
    int b = pix >> 10, p = pix & 1023;
    xb[o] = f2bf(in[((b * Tn + t) * 1024 + p) * CINc + c]);
}

// ---------------- prep: weights -> grouped B-fragment layout ----------------
// region layout: [kc][nh][j(0..7)][lane(0..63)][e(0..7)]; frag's nt = (j>>1)*4 + nh*2 + (j&1)
// element: k = kc*32 + (lane>>4)*4 + (e&3) + 16*(e>>2); n = nt*16 + (lane&15)
__global__ __launch_bounds__(256) void prep_w(const float* __restrict__ W0x,
                                              const float* __restrict__ W0h,
                                              const float* __restrict__ W1x,
                                              const float* __restrict__ W1h,
                                              ushort* __restrict__ F) {
    int o = blockIdx.x * 256 + threadIdx.x;
    if (o >= FR_TOTAL) return;
    const float* W; int K; int base;
    if (o < FR_L0H)      { W = W0x; K = 54;  base = FR_L0X; }
    else if (o < FR_L1X) { W = W0h; K = 576; base = FR_L0H; }
    else if (o < FR_L1H) { W = W1x; K = 576; base = FR_L1X; }
    else                 { W = W1h; K = 576; base = FR_L1H; }
    int r = o - base;
    int e = r & 7, lane = (r >> 3) & 63, j = (r >> 9) & 7, nh = (r >> 12) & 1, kc = r >> 13;
    int nt = ((j >> 1) << 2) + nh * 2 + (j & 1);
    int k = kc * 32 + ((lane >> 4) * 4) + (e & 3) + 16 * (e >> 2);
    int n = nt * 16 + (lane & 15);
    F[o] = (k < K) ? f2bf(W[k * 256 + n]) : (ushort)0;
}

// ---------------- prep: fold BN1 into dense layer ----------------
__global__ __launch_bounds__(640) void prep_dense(
    const float* __restrict__ dW, const float* __restrict__ dB,
    const float* __restrict__ g, const float* __restrict__ be,
    const float* __restrict__ mn, const float* __restrict__ vr,
    float* __restrict__ dWf, float* __restrict__ dBf)
{
    __shared__ float sc[64], sh[64];
    int tid = threadIdx.x;
    if (tid < 64) {
        float s = g[tid] * rsqrtf(vr[tid] + BN_EPS);
        sc[tid] = s; sh[tid] = be[tid] - mn[tid] * s;
    }
    __syncthreads();
    if (tid < 640) { int f = tid / 10; dWf[tid] = sc[f] * dW[tid]; }
    if (tid < NCc) {
        float a = dB[tid];
        for (int f = 0; f < 64; ++f) a += sh[f] * dW[f * 10 + tid];
        dBf[tid] = a;
    }
}

// ---------------- init ----------------
__global__ __launch_bounds__(256) void init_zero(float* c0, float* c1,
                                                 ushort* h0, ushort* h1,
                                                 ushort* h0b, ushort* h1b, float* out) {
    int i = blockIdx.x * 256 + threadIdx.x;
    if (i < PIX * Fc) { c0[i] = 0.f; c1[i] = 0.f; h0[i] = 0; h1[i] = 0; h0b[i] = 0; h1b[i] = 0; }
    if (i < Bsz * NCc) out[i] = 0.f;
}

// ---------------- 3-stage wavefront step, BK=64, 2m x 2n wave grid ----------------
// grp0 (blocks   0..255): layer-0 step t    (10 chunks: 1 x + 9 taps) -> h0, x1[t]
// grp1 (blocks 256..511): z1[t-1] = conv(x1[t-1],W1x)+b1 (9 taps) -> z1 frags (fp32)
// grp2 (blocks 512..767): layer-1 step t-2  (9 h-taps, acc init from z1) -> h1, h1s[t-2]
// Wave (wm,wn): 32 pixels (m-frags wm*32, wm*32+16) x 16 h-ch x 4 gates (n-frags g*4+nh*2+wn).
// B frags duplicated only across wm (2x), A across wn (2x): 48 b128-equiv/block-chunk vs 72.
__global__ __launch_bounds__(256, 3) void step_tri(
    int t,
    const ushort* __restrict__ Xb,
    const ushort* __restrict__ Bf0X, const ushort* __restrict__ Bf0H,
    const float* __restrict__ b0,
    float* __restrict__ C0, const ushort* __restrict__ H0prev, ushort* __restrict__ H0cur,
    ushort* __restrict__ X1s,
    const float* __restrict__ g0, const float* __restrict__ be0,
    const float* __restrict__ mn0, const float* __restrict__ v0,
    const ushort* __restrict__ Bf1X, const ushort* __restrict__ Bf1H,
    const float* __restrict__ b1, float* __restrict__ Z1,
    float* __restrict__ C1, const ushort* __restrict__ H1prev, ushort* __restrict__ H1cur,
    ushort* __restrict__ H1s)
{
    const int grp = blockIdx.x >> 8;
    int s;
    if (grp == 0)      { s = t;     if (s >= Tn) return; }
    else if (grp == 1) { s = t - 1; if (s < 0 || s >= Tn) return; }
    else               { s = t - 2; if (s < 0 || s >= Tn) return; }

    __shared__ ushort As[64 * 72];        // 64 rows x 64k bf16 + 16B pad = 144B rows
    __shared__ ushort Bs[2][8192];        // dbuf: 16KB B pair (2 sub-chunks of 8KB)

    const int tid = threadIdx.x;
    const int wid = tid >> 6, lane = tid & 63;
    const int wm = wid >> 1, wn = wid & 1;
    const int bid = blockIdx.x & 255;
    const int bm = bid >> 1, nh = bid & 1;
    const int m0 = bm * 64;

    const int p_local = tid >> 2, kq = tid & 3;
    const int p_global = m0 + p_local;
    const int img = p_global >> 10, pp = p_global & 1023;
    const int py = pp >> 5, px = pp & 31;

    // A-frag read bases (bytes): two m-frags per wave
    const int ar0 = (wm * 32 + 0  + (lane & 15)) * 144 + (lane >> 4) * 8;
    const int ar1 = (wm * 32 + 16 + (lane & 15)) * 144 + (lane >> 4) * 8;
    const int awr = p_local * 144 + kq * 16;                            // bytes

    // per-group bindings
    const ushort* __restrict__ Xt   = Xb + s * PIX * CINc;               // grp0 x-path
    const ushort* __restrict__ X1t  = X1s + (size_t)s * (PIX * Fc);      // grp1 input
    float* __restrict__ Zp = Z1 + (((size_t)s * 128 + bm) * 2 + nh) * 8192;  // grp1 out / grp2 in
    const int TOT = (grp == 0) ? 10 : 9;

    auto stageB = [&](int q, int buf) {
        const ushort *g0p, *g1p;
        if (grp == 0) {
            if (q == 0) { g0p = Bf0X + (nh << 12); g1p = Bf0X + ((2 + nh) << 12); }
            else { int tp = q - 1;
                   g0p = Bf0H + ((4 * tp + nh) << 12);
                   g1p = Bf0H + ((4 * tp + 2 + nh) << 12); }
        } else if (grp == 1) {
            g0p = Bf1X + ((4 * q + nh) << 12);
            g1p = Bf1X + ((4 * q + 2 + nh) << 12);
        } else {
            g0p = Bf1H + ((4 * q + nh) << 12);
            g1p = Bf1H + ((4 * q + 2 + nh) << 12);
        }
        ushort* d = &Bs[buf][0];
        GLDS(g0p + (tid << 3),         d + wid * 512);
        GLDS(g0p + ((256 + tid) << 3), d + 2048 + wid * 512);
        GLDS(g1p + (tid << 3),         d + 4096 + wid * 512);
        GLDS(g1p + ((256 + tid) << 3), d + 4096 + 2048 + wid * 512);
    };
    auto gather64 = [&](const ushort* __restrict__ P, int tap, uint4& a0, uint4& a1) {
        a0 = make_uint4(0u, 0u, 0u, 0u); a1 = a0;
        int dy = tap / 3 - 1, dx = tap % 3 - 1;
        int gy = py + dy, gx = px + dx;
        if ((unsigned)gy < 32u && (unsigned)gx < 32u) {
            const ushort* bp = P + (((img << 10) + gy * 32 + gx) << 6) + (kq << 3);
            a0 = *(const uint4*)bp;
            a1 = *(const uint4*)(bp + 32);
        }
    };
    auto gatherA = [&](int q, uint4& a0, uint4& a1) {
        if (grp == 0) {
            if (q == 0) {                        // x path, Ch=6, K=54 pad 64
                union { ushort s[8]; uint4 u; } p0, p1;
#pragma unroll
                for (int j = 0; j < 8; ++j) {
                    {
                        int kg = kq * 8 + j;     // < 54 always (kq<4)
                        int tap = kg / 6, c = kg - tap * 6;
                        int dy = tap / 3 - 1, dx = tap % 3 - 1;
                        int gy = py + dy, gx = px + dx;
                        ushort v = 0;
                        if ((unsigned)gy < 32u && (unsigned)gx < 32u)
                            v = Xt[((img << 10) + gy * 32 + gx) * 6 + c];
                        p0.s[j] = v;
                    }
                    {
                        int kg = 32 + kq * 8 + j;
                        ushort v = 0;
                        if (kg < 54) {
                            int tap = kg / 6, c = kg - tap * 6;
                            int dy = tap / 3 - 1, dx = tap % 3 - 1;
                            int gy = py + dy, gx = px + dx;
                            if ((unsigned)gy < 32u && (unsigned)gx < 32u)
                                v = Xt[((img << 10) + gy * 32 + gx) * 6 + c];
                        }
                        p1.s[j] = v;
                    }
                }
                a0 = p0.u; a1 = p1.u;
                return;
            }
            gather64(H0prev, q - 1, a0, a1);
        } else if (grp == 1) {
            gather64(X1t, q, a0, a1);
        } else {
            gather64(H1prev, q, a0, a1);
        }
    };

    // acc: 8 frags = gate g (0..3) x m-frag mf (0..1), index a = g*2 + mf
    float4v acc[8];
    if (grp == 2) {
#pragma unroll
        for (int a = 0; a < 8; ++a)
            acc[a] = *(const float4v*)(Zp + (((wid * 8 + a) * 64 + lane) << 2));
    } else {
        const float* __restrict__ bias = (grp == 0) ? b0 : b1;
        const int hch = (nh * 2 + wn) * 16 + (lane & 15);
#pragma unroll
        for (int g = 0; g < 4; ++g) {
            const float bb = bias[g * 64 + hch];
#pragma unroll
            for (int r = 0; r < 4; ++r) { acc[g * 2 + 0][r] = bb; acc[g * 2 + 1][r] = bb; }
        }
    }

    // prologue (two-barrier proven body)
    uint4 av0, av1;
    gatherA(0, av0, av1);
    stageB(0, 0);

    for (int q = 0; q < TOT; ++q) {
        __syncthreads();    // drains glds of B(q) + A loads; prior iter's LDS reads done
        *(uint4*)((char*)As + awr) = av0;
        *(uint4*)((char*)As + awr + 64) = av1;
        __syncthreads();    // publish As

        union { struct { uint2 lo, hi; } u; short8v s; } a00, a10, a01, a11;
        const char* base = (const char*)As;
        a00.u.lo = *(const uint2*)(base + ar0);      a00.u.hi = *(const uint2*)(base + ar0 + 32);
        a10.u.lo = *(const uint2*)(base + ar1);      a10.u.hi = *(const uint2*)(base + ar1 + 32);
        a01.u.lo = *(const uint2*)(base + ar0 + 64); a01.u.hi = *(const uint2*)(base + ar0 + 96);
        a11.u.lo = *(const uint2*)(base + ar1 + 64); a11.u.hi = *(const uint2*)(base + ar1 + 96);

        const ushort* bs = &Bs[q & 1][0];
        union { uint4 u; short8v s; } b0r[4], b1r[4];
#pragma unroll
        for (int g = 0; g < 4; ++g) {
            const int j = g * 2 + wn;
            b0r[g].u = *(const uint4*)(bs + ((j * 64 + lane) << 3));
            b1r[g].u = *(const uint4*)(bs + 4096 + ((j * 64 + lane) << 3));
        }

        if (q + 1 < TOT) {                      // prefetch during MFMA region
            stageB(q + 1, (q + 1) & 1);
            gatherA(q + 1, av0, av1);
        }

#pragma unroll
        for (int g = 0; g < 4; ++g) {
            acc[g * 2 + 0] = __builtin_amdgcn_mfma_f32_16x16x32_bf16(a00.s, b0r[g].s, acc[g * 2 + 0], 0, 0, 0);
            acc[g * 2 + 1] = __builtin_amdgcn_mfma_f32_16x16x32_bf16(a10.s, b0r[g].s, acc[g * 2 + 1], 0, 0, 0);
        }
#pragma unroll
        for (int g = 0; g < 4; ++g) {
            acc[g * 2 + 0] = __builtin_amdgcn_mfma_f32_16x16x32_bf16(a01.s, b1r[g].s, acc[g * 2 + 0], 0, 0, 0);
            acc[g * 2 + 1] = __builtin_amdgcn_mfma_f32_16x16x32_bf16(a11.s, b1r[g].s, acc[g * 2 + 1], 0, 0, 0);
        }
    }

    // ---------------- epilogues ----------------
    if (grp == 1) {                             // store z1 fragments (fp32, coalesced)
#pragma unroll
        for (int a = 0; a < 8; ++a) {
            float4 o;
            o.x = acc[a][0]; o.y = acc[a][1]; o.z = acc[a][2]; o.w = acc[a][3];
            *(float4*)(Zp + (((wid * 8 + a) * 64 + lane) << 2)) = o;
        }
        return;
    }

    // LSTM gate epilogue: g=0 -> i, 1 -> f, 2 -> g, 3 -> o
    float* __restrict__ C  = (grp == 0) ? C0 : C1;
    ushort* __restrict__ Hc = (grp == 0) ? H0cur : H1cur;
    ushort* __restrict__ Seq = (grp == 0) ? (X1s + (size_t)s * (PIX * Fc))
                                          : (H1s + (size_t)s * (PIX * Fc));
    const int ch = (nh * 2 + wn) * 16 + (lane & 15);   // h-channel 0..63
    float inv = 0.f, mu = 0.f, bet = 0.f;
    if (grp == 0) {
        inv = g0[ch] * rsqrtf(v0[ch] + BN_EPS);
        mu = mn0[ch]; bet = be0[ch];
    }
#pragma unroll
    for (int mf = 0; mf < 2; ++mf) {
#pragma unroll
        for (int r = 0; r < 4; ++r) {
            const int p = m0 + wm * 32 + mf * 16 + (lane >> 4) * 4 + r;
            const int o = p * 64 + ch;
            float zi = acc[0 + mf][r];
            float zf = acc[2 + mf][r];
            float zg = acc[4 + mf][r];
            float zo = acc[6 + mf][r];
            float cv = hsig(zf) * C[o] + hsig(zi) * tanhf(zg);
            C[o] = cv;
            float h = hsig(zo) * tanhf(cv);
            Hc[o] = f2bf(h);
            Seq[o] = (grp == 0) ? f2bf((h - mu) * inv + bet) : f2bf(h);
        }
    }
}

// ---------------- pool over all t: h1 @ dWf (BN folded) -> softmax -> mean ----------------
__global__ __launch_bounds__(256) void pool_all(
    const ushort* __restrict__ H1seq, const float* __restrict__ dWf,
    const float* __restrict__ dBf, float* __restrict__ out)
{
    __shared__ float wlds[640];
    __shared__ float accs[NCc];
    const int tid = threadIdx.x;
    for (int i = tid; i < 640; i += 256) wlds[i] = dWf[i];
    if (tid < NCc) accs[tid] = 0.f;
    __syncthreads();

    const int gid = blockIdx.x * 256 + tid;   // 512 blocks x 256 = 131072
    const int b = (gid & 8191) >> 10;          // uniform per block

    float logit[NCc];
#pragma unroll
    for (int c = 0; c < NCc; ++c) logit[c] = dBf[c];
    const ushort* hp = H1seq + (size_t)gid * Fc;
#pragma unroll
    for (int f0 = 0; f0 < 8; ++f0) {
        union { uint4 u; ushort s[8]; } hu;
        hu.u = *(const uint4*)(hp + f0 * 8);
#pragma unroll
        for (int j = 0; j < 8; ++j) {
            float v = bf2f(hu.s[j]);
            const float* w = &wlds[(f0 * 8 + j) * 10];
#pragma unroll
            for (int c = 0; c < NCc; ++c) logit[c] += v * w[c];
        }
    }
    float mx = logit[0];
#pragma unroll
    for (int c = 1; c < NCc; ++c) mx = fmaxf(mx, logit[c]);
    float p[NCc]; float ssum = 0.f;
#pragma unroll
    for (int c = 0; c < NCc; ++c) { p[c] = expf(logit[c] - mx); ssum += p[c]; }
    float invs = 1.f / ssum;

    // wave butterfly reduction per class, then one LDS atomic per wave
#pragma unroll
    for (int c = 0; c < NCc; ++c) {
        float v = p[c] * invs;
        v += __shfl_xor(v, 1);
        v += __shfl_xor(v, 2);
        v += __shfl_xor(v, 4);
        v += __shfl_xor(v, 8);
        v += __shfl_xor(v, 16);
        v += __shfl_xor(v, 32);
        if ((tid & 63) == 0) atomicAdd(&accs[c], v);
    }
    __syncthreads();
    if (tid < NCc)
        atomicAdd(&out[b * NCc + tid], accs[tid] * (1.0f / 16384.0f));
}

extern "C" void kernel_launch(void* const* d_in, const int* in_sizes, int n_in,
                              void* d_out, int out_size, void* d_ws, size_t ws_size,
                              hipStream_t stream) {
    const float* in    = (const float*)d_in[0];
    const float* l0Wx  = (const float*)d_in[1];
    const float* l0Wh  = (const float*)d_in[2];
    const float* l0b   = (const float*)d_in[3];
    const float* l0g   = (const float*)d_in[4];
    const float* l0be  = (const float*)d_in[5];
    const float* l0m   = (const float*)d_in[6];
    const float* l0v   = (const float*)d_in[7];
    const float* l1Wx  = (const float*)d_in[8];
    const float* l1Wh  = (const float*)d_in[9];
    const float* l1b   = (const float*)d_in[10];
    const float* l1g   = (const float*)d_in[11];
    const float* l1be  = (const float*)d_in[12];
    const float* l1m   = (const float*)d_in[13];
    const float* l1v   = (const float*)d_in[14];
    const float* dW    = (const float*)d_in[15];
    const float* dB    = (const float*)d_in[16];
    float* out = (float*)d_out;

    float* ws   = (float*)d_ws;
    float* c0   = ws;                        // 524,288 f
    float* c1   = c0 + 524288;
    float* z1   = c1 + 524288;               // 33,554,432 f (134 MB) z1 fragments
    ushort* us  = (ushort*)(z1 + 33554432);
    ushort* h0p0 = us;                       // h ping-pong buffers (bf16)
    ushort* h0p1 = h0p0 + 524288;
    ushort* h1p0 = h0p1 + 524288;
    ushort* h1p1 = h1p0 + 524288;
    ushort* xb  = h1p1 + 524288;             // 786,432 us
    ushort* x1  = xb + 786432;               // 16*524,288 us (BN'd layer-0 output)
    ushort* h1s = x1 + 8388608;              // 16*524,288 us (layer-1 h sequence)
    ushort* wf  = h1s + 8388608;             // 458,752 us
    float* dWf  = (float*)(wf + 458752);     // 640 f (BN-folded dense W)
    float* dBf  = dWf + 640;                 // 10 f

    ushort* h0p[2] = { h0p0, h0p1 };
    ushort* h1p[2] = { h1p0, h1p1 };

    prep_x<<<3072, 256, 0, stream>>>(in, xb);
    prep_w<<<1792, 256, 0, stream>>>(l0Wx, l0Wh, l1Wx, l1Wh, wf);
    prep_dense<<<1, 640, 0, stream>>>(dW, dB, l1g, l1be, l1m, l1v, dWf, dBf);
    init_zero<<<2048, 256, 0, stream>>>(c0, c1, h0p0, h1p0, h0p1, h1p1, out);

    // 3-stage wavefront: slot t = { L0 step t, z1[t-1], L1 step t-2 }
    for (int t = 0; t < Tn + 2; ++t) {
        step_tri<<<768, 256, 0, stream>>>(
            t, xb,
            wf + FR_L0X, wf + FR_L0H, l0b,
            c0, h0p[t & 1], h0p[(t + 1) & 1], x1,
            l0g, l0be, l0m, l0v,
            wf + FR_L1X, wf + FR_L1H, l1b, z1,
            c1, h1p[t & 1], h1p[(t + 1) & 1], h1s);
    }
    pool_all<<<512, 256, 0, stream>>>(h1s, dWf, dBf, out);
}

// Round 11
// 330.709 us; speedup vs baseline: 1.1301x; 1.1301x over previous
//
#include <hip/hip_runtime.h>
#include <math.h>

typedef __attribute__((ext_vector_type(8))) short short8v;   // 8 bf16 = 4 VGPRs
typedef __attribute__((ext_vector_type(4))) float float4v;   // MFMA acc

constexpr int Bsz = 8, Tn = 16, CINc = 6, Fc = 64, NCc = 10;
constexpr int PIX = 8192;                 // 8*32*32 pixels per timestep
constexpr float BN_EPS = 1e-3f;

// weight-fragment region offsets (in ushort elements)
constexpr int FR_L0X = 0;                 // 2 chunks  (K=54 padded to 64)
constexpr int FR_L0H = 16384;             // 18 chunks (K=576)
constexpr int FR_L1X = 163840;            // 18 chunks
constexpr int FR_L1H = 311296;            // 18 chunks
constexpr int FR_TOTAL = 458752;

__device__ __forceinline__ ushort f2bf(float f) {
    union { float f; unsigned u; } v; v.f = f;
    unsigned r = v.u + 0x7FFFu + ((v.u >> 16) & 1u);   // RNE
    return (ushort)(r >> 16);
}
__device__ __forceinline__ float bf2f(ushort u) {
    union { unsigned u; float f; } v; v.u = ((unsigned)u) << 16; return v.f;
}
__device__ __forceinline__ float hsig(float x) {
    return fminf(fmaxf(0.2f * x + 0.5f, 0.0f), 1.0f);
}

#define GLDS(srcp, dstp) \
    __builtin_amdgcn_global_load_lds((const __attribute__((address_space(1))) void*)(srcp), \
                                     (__attribute__((address_space(3))) void*)(dstp), 16, 0, 0)

// ---------------- prep: x -> bf16 [t][pix][6] ----------------
__global__ __launch_bounds__(256) void prep_x(const float* __restrict__ in,
                                              ushort* __restrict__ xb) {
    int o = blockIdx.x * 256 + threadIdx.x;        // 16*8192*6 = 786432
    if (o >= Tn * PIX * CINc) return;
    int t = o / (PIX * CINc);
    int rem = o - t * (PIX * CINc);
    int pix = rem / CINc, c = rem - pix * CINc;
    int b = pix >> 10, p = pix & 1023;
    xb[o] = f2bf(in[((b * Tn + t) * 1024 + p) * CINc + c]);
}

// ---------------- prep: weights -> grouped B-fragment layout ----------------
// region layout: [kc][nh][j(0..7)][lane(0..63)][e(0..7)]; frag's nt = (j>>1)*4 + nh*2 + (j&1)
// element: k = kc*32 + (lane>>4)*4 + (e&3) + 16*(e>>2); n = nt*16 + (lane&15)
__global__ __launch_bounds__(256) void prep_w(const float* __restrict__ W0x,
                                              const float* __restrict__ W0h,
                                              const float* __restrict__ W1x,
                                              const float* __restrict__ W1h,
                                              ushort* __restrict__ F) {
    int o = blockIdx.x * 256 + threadIdx.x;
    if (o >= FR_TOTAL) return;
    const float* W; int K; int base;
    if (o < FR_L0H)      { W = W0x; K = 54;  base = FR_L0X; }
    else if (o < FR_L1X) { W = W0h; K = 576; base = FR_L0H; }
    else if (o < FR_L1H) { W = W1x; K = 576; base = FR_L1X; }
    else                 { W = W1h; K = 576; base = FR_L1H; }
    int r = o - base;
    int e = r & 7, lane = (r >> 3) & 63, j = (r >> 9) & 7, nh = (r >> 12) & 1, kc = r >> 13;
    int nt = ((j >> 1) << 2) + nh * 2 + (j & 1);
    int k = kc * 32 + ((lane >> 4) * 4) + (e & 3) + 16 * (e >> 2);
    int n = nt * 16 + (lane & 15);
    F[o] = (k < K) ? f2bf(W[k * 256 + n]) : (ushort)0;
}

// ---------------- prep: fold BN1 into dense layer ----------------
__global__ __launch_bounds__(640) void prep_dense(
    const float* __restrict__ dW, const float* __restrict__ dB,
    const float* __restrict__ g, const float* __restrict__ be,
    const float* __restrict__ mn, const float* __restrict__ vr,
    float* __restrict__ dWf, float* __restrict__ dBf)
{
    __shared__ float sc[64], sh[64];
    int tid = threadIdx.x;
    if (tid < 64) {
        float s = g[tid] * rsqrtf(vr[tid] + BN_EPS);
        sc[tid] = s; sh[tid] = be[tid] - mn[tid] * s;
    }
    __syncthreads();
    if (tid < 640) { int f = tid / 10; dWf[tid] = sc[f] * dW[tid]; }
    if (tid < NCc) {
        float a = dB[tid];
        for (int f = 0; f < 64; ++f) a += sh[f] * dW[f * 10 + tid];
        dBf[tid] = a;
    }
}

// ---------------- init ----------------
__global__ __launch_bounds__(256) void init_zero(float* c0, float* c1,
                                                 ushort* h0, ushort* h1,
                                                 ushort* h0b, ushort* h1b, float* out) {
    int i = blockIdx.x * 256 + threadIdx.x;
    if (i < PIX * Fc) { c0[i] = 0.f; c1[i] = 0.f; h0[i] = 0; h1[i] = 0; h0b[i] = 0; h1b[i] = 0; }
    if (i < Bsz * NCc) out[i] = 0.f;
}

// ---------------- 3-stage wavefront step, halo-LDS A path ----------------
// grp0 (blocks   0..255): layer-0 step t    (10 chunks: 1 x + 9 taps) -> h0, x1[t]
// grp1 (blocks 256..511): z1[t-1] = conv(x1[t-1],W1x)+b1 (9 taps) -> z1 frags (fp32)
// grp2 (blocks 512..767): layer-1 step t-2  (9 h-taps, acc init from z1) -> h1, h1s[t-2]
// Block tile: 64 pixels (2 rows x 32 cols) x 128 gate-paired ch (nh half).
// A input staged ONCE as a 4x34x64ch halo in LDS; per-tap A frags are direct b64 LDS
// reads at shifted offsets. One barrier per chunk (B glds dbuf drain only).
__global__ __launch_bounds__(256, 3) void step_tri(
    int t,
    const ushort* __restrict__ Xb,
    const ushort* __restrict__ Bf0X, const ushort* __restrict__ Bf0H,
    const float* __restrict__ b0,
    float* __restrict__ C0, const ushort* __restrict__ H0prev, ushort* __restrict__ H0cur,
    ushort* __restrict__ X1s,
    const float* __restrict__ g0, const float* __restrict__ be0,
    const float* __restrict__ mn0, const float* __restrict__ v0,
    const ushort* __restrict__ Bf1X, const ushort* __restrict__ Bf1H,
    const float* __restrict__ b1, float* __restrict__ Z1,
    float* __restrict__ C1, const ushort* __restrict__ H1prev, ushort* __restrict__ H1cur,
    ushort* __restrict__ H1s)
{
    const int grp = blockIdx.x >> 8;
    int s;
    if (grp == 0)      { s = t;     if (s >= Tn) return; }
    else if (grp == 1) { s = t - 1; if (s < 0 || s >= Tn) return; }
    else               { s = t - 2; if (s < 0 || s >= Tn) return; }

    __shared__ ushort Hh[136 * 68];       // 64-ch halo: [yy*34+xx][68] (64 used, 68 = bank spread)
    __shared__ ushort Xh[136 * 8];        // grp0 x-halo: [yy*34+xx][8] (6 used)
    __shared__ ushort Bs[2][8192];        // dbuf: 16KB B pair

    const int tid = threadIdx.x;
    const int wid = tid >> 6, lane = tid & 63;
    const int wm = wid >> 1, wn = wid & 1;
    const int bid = blockIdx.x & 255;
    const int bm = bid >> 1, nh = bid & 1;
    const int m0 = bm * 64;
    const int img = m0 >> 10;
    const int py0 = (m0 & 1023) >> 5;     // first of the 2 pixel rows

    // per-group bindings
    const ushort* __restrict__ Xt   = Xb + s * PIX * CINc;               // grp0 x-path
    const ushort* __restrict__ X1t  = X1s + (size_t)s * (PIX * Fc);      // grp1 input
    float* __restrict__ Zp = Z1 + (((size_t)s * 128 + bm) * 2 + nh) * 8192;  // grp1 out / grp2 in
    const int TOT = (grp == 0) ? 10 : 9;
    const ushort* __restrict__ Psrc = (grp == 0) ? H0prev : (grp == 1 ? X1t : H1prev);

    auto stageB = [&](int q, int buf) {
        const ushort *g0p, *g1p;
        if (grp == 0) {
            if (q == 0) { g0p = Bf0X + (nh << 12); g1p = Bf0X + ((2 + nh) << 12); }
            else { int tp = q - 1;
                   g0p = Bf0H + ((4 * tp + nh) << 12);
                   g1p = Bf0H + ((4 * tp + 2 + nh) << 12); }
        } else if (grp == 1) {
            g0p = Bf1X + ((4 * q + nh) << 12);
            g1p = Bf1X + ((4 * q + 2 + nh) << 12);
        } else {
            g0p = Bf1H + ((4 * q + nh) << 12);
            g1p = Bf1H + ((4 * q + 2 + nh) << 12);
        }
        ushort* d = &Bs[buf][0];
        GLDS(g0p + (tid << 3),         d + wid * 512);
        GLDS(g0p + ((256 + tid) << 3), d + 2048 + wid * 512);
        GLDS(g1p + (tid << 3),         d + 4096 + wid * 512);
        GLDS(g1p + ((256 + tid) << 3), d + 4096 + 2048 + wid * 512);
    };

    // ---- prologue: stage halo(s) + B(0) ----
    stageB(0, 0);
    // 64-ch halo: 136 slots x 8 parts of 16B = 1088 units
#pragma unroll
    for (int u = 0; u < 5; ++u) {
        int idx = tid + u * 256;
        if (idx < 1088) {
            int slot = idx >> 3, part = idx & 7;
            int yy = slot / 34, xx = slot - yy * 34;
            int gy = py0 - 1 + yy, gx = xx - 1;
            uint4 v = make_uint4(0u, 0u, 0u, 0u);
            if ((unsigned)gy < 32u && (unsigned)gx < 32u)
                v = *(const uint4*)(Psrc + (((img << 10) + gy * 32 + gx) << 6) + part * 8);
            ushort* d = &Hh[slot * 68 + part * 8];
            *(uint2*)(d)     = make_uint2(v.x, v.y);   // 8B-aligned (row stride 136B)
            *(uint2*)(d + 4) = make_uint2(v.z, v.w);
        }
    }
    if (grp == 0) {                       // x-halo: 136 slots x 6 ch
#pragma unroll
        for (int u = 0; u < 4; ++u) {
            int idx = tid + u * 256;
            if (idx < 816) {
                int slot = idx / 6, c = idx - slot * 6;
                int yy = slot / 34, xx = slot - yy * 34;
                int gy = py0 - 1 + yy, gx = xx - 1;
                ushort v = 0;
                if ((unsigned)gy < 32u && (unsigned)gx < 32u)
                    v = Xt[((img << 10) + gy * 32 + gx) * 6 + c];
                Xh[slot * 8 + c] = v;
            }
        }
    }

    // acc: 8 frags = gate g (0..3) x m-frag mf (0..1), index a = g*2 + mf
    float4v acc[8];
    if (grp == 2) {
#pragma unroll
        for (int a = 0; a < 8; ++a)
            acc[a] = *(const float4v*)(Zp + (((wid * 8 + a) * 64 + lane) << 2));
    } else {
        const float* __restrict__ bias = (grp == 0) ? b0 : b1;
        const int hch = (nh * 2 + wn) * 16 + (lane & 15);
#pragma unroll
        for (int g = 0; g < 4; ++g) {
            const float bb = bias[g * 64 + hch];
#pragma unroll
            for (int r = 0; r < 4; ++r) { acc[g * 2 + 0][r] = bb; acc[g * 2 + 1][r] = bb; }
        }
    }

    // lane pixel coords for the two m-frags
    const int p0x = wm * 32 + (lane & 15);        // mf=0
    const int p1x = p0x + 16;                     // mf=1
    const int y0r = p0x >> 5, x0c = p0x & 31;
    const int y1r = p1x >> 5, x1c = p1x & 31;
    const int coff = (lane >> 4) << 2;            // c base (ushorts)

    // x-path frag builder (grp0 chunk 0): per-element gather from Xh
    auto xfrag = [&](int lry, int lcx, int half) -> short8v {
        union { ushort e[8]; short8v v; } r;
#pragma unroll
        for (int e = 0; e < 8; ++e) {
            int kg = half * 32 + coff + (e & 3) + 16 * (e >> 2);
            ushort val = 0;
            if (kg < 54) {
                int tap = kg / 6, c = kg - tap * 6;
                int dy = tap / 3 - 1, dxx = tap % 3 - 1;
                val = Xh[((lry + dy + 1) * 34 + (lcx + dxx + 1)) * 8 + c];
            }
            r.e[e] = val;
        }
        return r.v;
    };

    __syncthreads();    // publish halos + Bs[0]

    for (int q = 0; q < TOT; ++q) {
        if (q + 1 < TOT) stageB(q + 1, (q + 1) & 1);   // full chunk body in flight

        union { struct { uint2 lo, hi; } u; short8v s; } a00, a10, a01, a11;
        if (grp == 0 && q == 0) {
            a00.s = xfrag(y0r, x0c, 0); a01.s = xfrag(y0r, x0c, 1);
            a10.s = xfrag(y1r, x1c, 0); a11.s = xfrag(y1r, x1c, 1);
        } else {
            const int tap = (grp == 0) ? q - 1 : q;
            const int dy = tap / 3 - 1, dxx = tap % 3 - 1;
            const ushort* h0r = &Hh[((y0r + dy + 1) * 34 + (x0c + dxx + 1)) * 68 + coff];
            const ushort* h1r = &Hh[((y1r + dy + 1) * 34 + (x1c + dxx + 1)) * 68 + coff];
            a00.u.lo = *(const uint2*)(h0r);      a00.u.hi = *(const uint2*)(h0r + 16);
            a01.u.lo = *(const uint2*)(h0r + 32); a01.u.hi = *(const uint2*)(h0r + 48);
            a10.u.lo = *(const uint2*)(h1r);      a10.u.hi = *(const uint2*)(h1r + 16);
            a11.u.lo = *(const uint2*)(h1r + 32); a11.u.hi = *(const uint2*)(h1r + 48);
        }

        const ushort* bs = &Bs[q & 1][0];
        union { uint4 u; short8v s; } b0r[4], b1r[4];
#pragma unroll
        for (int g = 0; g < 4; ++g) {
            const int j = g * 2 + wn;
            b0r[g].u = *(const uint4*)(bs + ((j * 64 + lane) << 3));
            b1r[g].u = *(const uint4*)(bs + 4096 + ((j * 64 + lane) << 3));
        }

#pragma unroll
        for (int g = 0; g < 4; ++g) {
            acc[g * 2 + 0] = __builtin_amdgcn_mfma_f32_16x16x32_bf16(a00.s, b0r[g].s, acc[g * 2 + 0], 0, 0, 0);
            acc[g * 2 + 1] = __builtin_amdgcn_mfma_f32_16x16x32_bf16(a10.s, b0r[g].s, acc[g * 2 + 1], 0, 0, 0);
        }
#pragma unroll
        for (int g = 0; g < 4; ++g) {
            acc[g * 2 + 0] = __builtin_amdgcn_mfma_f32_16x16x32_bf16(a01.s, b1r[g].s, acc[g * 2 + 0], 0, 0, 0);
            acc[g * 2 + 1] = __builtin_amdgcn_mfma_f32_16x16x32_bf16(a11.s, b1r[g].s, acc[g * 2 + 1], 0, 0, 0);
        }

        __syncthreads();   // drains glds of B(q+1); ends reads of Bs[q&1]
    }

    // ---------------- epilogues ----------------
    if (grp == 1) {                             // store z1 fragments (fp32, coalesced)
#pragma unroll
        for (int a = 0; a < 8; ++a) {
            float4 o;
            o.x = acc[a][0]; o.y = acc[a][1]; o.z = acc[a][2]; o.w = acc[a][3];
            *(float4*)(Zp + (((wid * 8 + a) * 64 + lane) << 2)) = o;
        }
        return;
    }

    // LSTM gate epilogue: g=0 -> i, 1 -> f, 2 -> g, 3 -> o
    float* __restrict__ C  = (grp == 0) ? C0 : C1;
    ushort* __restrict__ Hc = (grp == 0) ? H0cur : H1cur;
    ushort* __restrict__ Seq = (grp == 0) ? (X1s + (size_t)s * (PIX * Fc))
                                          : (H1s + (size_t)s * (PIX * Fc));
    const int ch = (nh * 2 + wn) * 16 + (lane & 15);   // h-channel 0..63
    float inv = 0.f, mu = 0.f, bet = 0.f;
    if (grp == 0) {
        inv = g0[ch] * rsqrtf(v0[ch] + BN_EPS);
        mu = mn0[ch]; bet = be0[ch];
    }
#pragma unroll
    for (int mf = 0; mf < 2; ++mf) {
#pragma unroll
        for (int r = 0; r < 4; ++r) {
            const int p = m0 + wm * 32 + mf * 16 + (lane >> 4) * 4 + r;
            const int o = p * 64 + ch;
            float zi = acc[0 + mf][r];
            float zf = acc[2 + mf][r];
            float zg = acc[4 + mf][r];
            float zo = acc[6 + mf][r];
            float cv = hsig(zf) * C[o] + hsig(zi) * tanhf(zg);
            C[o] = cv;
            float h = hsig(zo) * tanhf(cv);
            Hc[o] = f2bf(h);
            Seq[o] = (grp == 0) ? f2bf((h - mu) * inv + bet) : f2bf(h);
        }
    }
}

// ---------------- pool over all t: h1 @ dWf (BN folded) -> softmax -> mean ----------------
__global__ __launch_bounds__(256) void pool_all(
    const ushort* __restrict__ H1seq, const float* __restrict__ dWf,
    const float* __restrict__ dBf, float* __restrict__ out)
{
    __shared__ float wlds[640];
    __shared__ float accs[NCc];
    const int tid = threadIdx.x;
    for (int i = tid; i < 640; i += 256) wlds[i] = dWf[i];
    if (tid < NCc) accs[tid] = 0.f;
    __syncthreads();

    const int gid = blockIdx.x * 256 + tid;   // 512 blocks x 256 = 131072
    const int b = (gid & 8191) >> 10;          // uniform per block

    float logit[NCc];
#pragma unroll
    for (int c = 0; c < NCc; ++c) logit[c] = dBf[c];
    const ushort* hp = H1seq + (size_t)gid * Fc;
#pragma unroll
    for (int f0 = 0; f0 < 8; ++f0) {
        union { uint4 u; ushort s[8]; } hu;
        hu.u = *(const uint4*)(hp + f0 * 8);
#pragma unroll
        for (int j = 0; j < 8; ++j) {
            float v = bf2f(hu.s[j]);
            const float* w = &wlds[(f0 * 8 + j) * 10];
#pragma unroll
            for (int c = 0; c < NCc; ++c) logit[c] += v * w[c];
        }
    }
    float mx = logit[0];
#pragma unroll
    for (int c = 1; c < NCc; ++c) mx = fmaxf(mx, logit[c]);
    float p[NCc]; float ssum = 0.f;
#pragma unroll
    for (int c = 0; c < NCc; ++c) { p[c] = expf(logit[c] - mx); ssum += p[c]; }
    float invs = 1.f / ssum;

    // wave butterfly reduction per class, then one LDS atomic per wave
#pragma unroll
    for (int c = 0; c < NCc; ++c) {
        float v = p[c] * invs;
        v += __shfl_xor(v, 1);
        v += __shfl_xor(v, 2);
        v += __shfl_xor(v, 4);
        v += __shfl_xor(v, 8);
        v += __shfl_xor(v, 16);
        v += __shfl_xor(v, 32);
        if ((tid & 63) == 0) atomicAdd(&accs[c], v);
    }
    __syncthreads();
    if (tid < NCc)
        atomicAdd(&out[b * NCc + tid], accs[tid] * (1.0f / 16384.0f));
}

extern "C" void kernel_launch(void* const* d_in, const int* in_sizes, int n_in,
                              void* d_out, int out_size, void* d_ws, size_t ws_size,
                              hipStream_t stream) {
    const float* in    = (const float*)d_in[0];
    const float* l0Wx  = (const float*)d_in[1];
    const float* l0Wh  = (const float*)d_in[2];
    const float* l0b   = (const float*)d_in[3];
    const float* l0g   = (const float*)d_in[4];
    const float* l0be  = (const float*)d_in[5];
    const float* l0m   = (const float*)d_in[6];
    const float* l0v   = (const float*)d_in[7];
    const float* l1Wx  = (const float*)d_in[8];
    const float* l1Wh  = (const float*)d_in[9];
    const float* l1b   = (const float*)d_in[10];
    const float* l1g   = (const float*)d_in[11];
    const float* l1be  = (const float*)d_in[12];
    const float* l1m   = (const float*)d_in[13];
    const float* l1v   = (const float*)d_in[14];
    const float* dW    = (const float*)d_in[15];
    const float* dB    = (const float*)d_in[16];
    float* out = (float*)d_out;

    float* ws   = (float*)d_ws;
    float* c0   = ws;                        // 524,288 f
    float* c1   = c0 + 524288;
    float* z1   = c1 + 524288;               // 33,554,432 f (134 MB) z1 fragments
    ushort* us  = (ushort*)(z1 + 33554432);
    ushort* h0p0 = us;                       // h ping-pong buffers (bf16)
    ushort* h0p1 = h0p0 + 524288;
    ushort* h1p0 = h0p1 + 524288;
    ushort* h1p1 = h1p0 + 524288;
    ushort* xb  = h1p1 + 524288;             // 786,432 us
    ushort* x1  = xb + 786432;               // 16*524,288 us (BN'd layer-0 output)
    ushort* h1s = x1 + 8388608;              // 16*524,288 us (layer-1 h sequence)
    ushort* wf  = h1s + 8388608;             // 458,752 us
    float* dWf  = (float*)(wf + 458752);     // 640 f (BN-folded dense W)
    float* dBf  = dWf + 640;                 // 10 f

    ushort* h0p[2] = { h0p0, h0p1 };
    ushort* h1p[2] = { h1p0, h1p1 };

    prep_x<<<3072, 256, 0, stream>>>(in, xb);
    prep_w<<<1792, 256, 0, stream>>>(l0Wx, l0Wh, l1Wx, l1Wh, wf);
    prep_dense<<<1, 640, 0, stream>>>(dW, dB, l1g, l1be, l1m, l1v, dWf, dBf);
    init_zero<<<2048, 256, 0, stream>>>(c0, c1, h0p0, h1p0, h0p1, h1p1, out);

    // 3-stage wavefront: slot t = { L0 step t, z1[t-1], L1 step t-2 }
    for (int t = 0; t < Tn + 2; ++t) {
        step_tri<<<768, 256, 0, stream>>>(
            t, xb,
            wf + FR_L0X, wf + FR_L0H, l0b,
            c0, h0p[t & 1], h0p[(t + 1) & 1], x1,
            l0g, l0be, l0m, l0v,
            wf + FR_L1X, wf + FR_L1H, l1b, z1,
            c1, h1p[t & 1], h1p[(t + 1) & 1], h1s);
    }
    pool_all<<<512, 256, 0, stream>>>(h1s, dWf, dBf, out);
}